// Round 19
// baseline (119.377 us; speedup 1.0000x reference)
//
#include <hip/hip_runtime.h>
#include <hip/hip_fp16.h>
#include <math.h>

#define NN 30000
#define KK 32
#define FF 256
#define DD 128
#define NB16 1875   // 30000 / 16 exactly
#define SA 268      // padded f16 row stride for LDS fragment arrays

typedef _Float16 f16x8 __attribute__((ext_vector_type(8)));
typedef _Float16 f16x2 __attribute__((ext_vector_type(2)));
typedef float f32x4v __attribute__((ext_vector_type(4)));

__device__ __forceinline__ float seluf(float x) {
    const float scale = 1.0507009873554804934193349852946f;
    const float alpha = 1.6732632423543772848170429916717f;
    return x > 0.f ? scale * x : scale * alpha * expm1f(x);
}

__device__ __forceinline__ float waveReduceSum(float v) {
#pragma unroll
    for (int m = 1; m < 64; m <<= 1) v += __shfl_xor(v, m, 64);
    return v;
}

// -------- kernel 0: transposed f16 weight tables ---------------------------
__global__ __launch_bounds__(256) void k_prep(
    const float* __restrict__ W, const float* __restrict__ M,
    _Float16* __restrict__ Wt, _Float16* __restrict__ Lt)
{
    const int b = blockIdx.x, t = threadIdx.x;
    if (b < 128) {
        Wt[b * FF + t] = (_Float16)W[t * DD + b];
    } else if (t < 128) {
        const int c = b - 128, k = t;
        const float v = (k == 0 && c == 0) ? 1.f
                      : ((k >= 1 && c >= 1) ? M[(k - 1) * 127 + (c - 1)] : 0.f);
        Lt[c * DD + k] = (_Float16)v;
    }
}

// -------- kernel 1: table0 = msg_aux(normalize(expmap(selu(x@W+b))) @ lw) --
// (round-16 version: 4 waves / 16 rows, LDS overlay)
__global__ __launch_bounds__(256) void k_lin_exp_msg(
    const float* __restrict__ x, const _Float16* __restrict__ Wt,
    const float* __restrict__ b, const _Float16* __restrict__ Lt,
    __half* __restrict__ table)
{
    __shared__ _Float16 hhi[16][SA];    // phase 0/1: x-f16 staging; later: h hi
    __shared__ _Float16 hlo[16][SA];
    __shared__ float red[4][16];
    __shared__ float m0s[16];
    const int wv_ = threadIdx.x >> 6;
    const int lane = threadIdx.x & 63;
    const int g = lane >> 4, c16 = lane & 15;
    const int baseRow = blockIdx.x * 16;
    const int nb = wv_ * 2;
    const int arow = baseRow + c16;

    {
        const float4* xp = (const float4*)(x + (size_t)arow * FF);
#pragma unroll
        for (int i = 0; i < 2; ++i) {
            const int ks = wv_ * 2 + i;
            const float4 f0 = xp[ks * 8 + g * 2];
            const float4 f1 = xp[ks * 8 + g * 2 + 1];
            const float q[8] = {f0.x, f0.y, f0.z, f0.w, f1.x, f1.y, f1.z, f1.w};
            f16x8 a;
#pragma unroll
            for (int j = 0; j < 8; ++j) a[j] = (_Float16)q[j];
            *(f16x8*)&hhi[c16][ks * 32 + g * 8] = a;
        }
    }
    __syncthreads();

    f16x8 bw0[8], bw1[8];
#pragma unroll
    for (int ks = 0; ks < 8; ++ks) {
        bw0[ks] = *(const f16x8*)(Wt + (size_t)((nb + 0) * 16 + c16) * FF + ks * 32 + g * 8);
        bw1[ks] = *(const f16x8*)(Wt + (size_t)((nb + 1) * 16 + c16) * FF + ks * 32 + g * 8);
    }
    f16x8 af[8];
#pragma unroll
    for (int ks = 0; ks < 8; ++ks)
        af[ks] = *(const f16x8*)&hhi[c16][ks * 32 + g * 8];

    f32x4v acc[2];
    acc[0] = acc[1] = f32x4v{0.f, 0.f, 0.f, 0.f};
#pragma unroll
    for (int ks = 0; ks < 8; ++ks) {
        acc[0] = __builtin_amdgcn_mfma_f32_16x16x32_f16(af[ks], bw0[ks], acc[0], 0, 0, 0);
        acc[1] = __builtin_amdgcn_mfma_f32_16x16x32_f16(af[ks], bw1[ks], acc[1], 0, 0, 0);
    }

    float bias[2];
#pragma unroll
    for (int n = 0; n < 2; ++n) bias[n] = b[(nb + n) * 16 + c16];

    float vv[4][2];
#pragma unroll
    for (int r = 0; r < 4; ++r) {
        float part = 0.f;
#pragma unroll
        for (int n = 0; n < 2; ++n) {
            vv[r][n] = seluf(acc[n][r] + bias[n]);
            float sq = vv[r][n] * vv[r][n];
            if (wv_ == 0 && n == 0 && c16 == 0) sq = 0.f;
            part += sq;
        }
#pragma unroll
        for (int m = 1; m < 16; m <<= 1) part += __shfl_xor(part, m, 64);
        if (c16 == 0) red[wv_][4 * g + r] = part;
    }
    __syncthreads();
#pragma unroll
    for (int r = 0; r < 4; ++r) {
        const int lrow = 4 * g + r;
        const float ldv = red[0][lrow] + red[1][lrow] + red[2][lrow] + red[3][lrow];
        const float nd = sqrtf(fmaxf(ldv + 1e-9f, 1e-10f));
        const float t  = fminf(nd, 1.0f);
        const float sc = sinhf(t) / nd;
        const float tm = sqrtf(1.f + sc * sc * ldv);
#pragma unroll
        for (int n = 0; n < 2; ++n) {
            const int col = (nb + n) * 16 + c16;
            const float o = (wv_ == 0 && n == 0 && c16 == 0) ? tm : sc * vv[r][n];
            const _Float16 hi = (_Float16)o;
            hhi[lrow][col] = hi;
            hlo[lrow][col] = (_Float16)(o - (float)hi);
        }
    }
    __syncthreads();

    f16x8 bl0[4], bl1[4];
#pragma unroll
    for (int ks = 0; ks < 4; ++ks) {
        bl0[ks] = *(const f16x8*)(Lt + (size_t)((nb + 0) * 16 + c16) * DD + ks * 32 + g * 8);
        bl1[ks] = *(const f16x8*)(Lt + (size_t)((nb + 1) * 16 + c16) * DD + ks * 32 + g * 8);
    }
    f16x8 mh[4], ml[4];
#pragma unroll
    for (int ks = 0; ks < 4; ++ks) {
        mh[ks] = *(const f16x8*)&hhi[c16][ks * 32 + g * 8];
        ml[ks] = *(const f16x8*)&hlo[c16][ks * 32 + g * 8];
    }
    acc[0] = acc[1] = f32x4v{0.f, 0.f, 0.f, 0.f};
#pragma unroll
    for (int ks = 0; ks < 4; ++ks) {
        acc[0] = __builtin_amdgcn_mfma_f32_16x16x32_f16(mh[ks], bl0[ks], acc[0], 0, 0, 0);
        acc[0] = __builtin_amdgcn_mfma_f32_16x16x32_f16(ml[ks], bl0[ks], acc[0], 0, 0, 0);
        acc[1] = __builtin_amdgcn_mfma_f32_16x16x32_f16(mh[ks], bl1[ks], acc[1], 0, 0, 0);
        acc[1] = __builtin_amdgcn_mfma_f32_16x16x32_f16(ml[ks], bl1[ks], acc[1], 0, 0, 0);
    }

#pragma unroll
    for (int r = 0; r < 4; ++r) {
        float part = 0.f;
#pragma unroll
        for (int n = 0; n < 2; ++n) {
            float sq = acc[n][r] * acc[n][r];
            if (wv_ == 0 && n == 0 && c16 == 0) sq = 0.f;
            part += sq;
        }
#pragma unroll
        for (int m = 1; m < 16; m <<= 1) part += __shfl_xor(part, m, 64);
        if (c16 == 0) red[wv_][4 * g + r] = part;
        if (wv_ == 0 && c16 == 0) m0s[4 * g + r] = acc[0][r];
    }
    __syncthreads();
#pragma unroll
    for (int r = 0; r < 4; ++r) {
        const int lrow = 4 * g + r;
        const int row = baseRow + lrow;
        const float rn = 1.f / m0s[lrow];
        const float sum2 = red[0][lrow] + red[1][lrow] + red[2][lrow] + red[3][lrow];
        float kn = sum2 * rn * rn;
        kn = fminf(fmaxf(kn, 0.f), 0.9f);
        const float fh = 1.f / sqrtf(1.f - kn);
#pragma unroll
        for (int n = 0; n < 2; ++n) {
            const float val = (wv_ == 0 && n == 0 && c16 == 0) ? fh : acc[n][r] * rn;
            table[(size_t)row * DD + (nb + n) * 16 + c16] = __float2half(val);
        }
    }
}

// -------- kernel 2a: layer-0 aggregation, h written as exact f16 hi/lo -----
// Identical structure to the proven standalone k_layer (1 node/wave, max
// outstanding-miss concurrency); epilogue stores hi/lo pair instead of fp32.
__global__ __launch_bounds__(256) void k_layer_h(
    const __half* __restrict__ tin, const int* __restrict__ adj,
    const float* __restrict__ w,
    _Float16* __restrict__ hhi_g, _Float16* __restrict__ hlo_g)
{
    const int wave = threadIdx.x >> 6;
    const int lane = threadIdx.x & 63;
    const int node = blockIdx.x * 4 + wave;

    const int   av = adj[node * KK + (lane & 31)];
    const float wv = w[node * KK + (lane & 31)];

    unsigned int vbits[32];
#pragma unroll
    for (int j = 0; j < KK; ++j) {
        const int idx = __shfl(av, j, 64);
        vbits[j] = *(const unsigned int*)(tin + (size_t)idx * DD + lane * 2);
    }

    const float f  = __half2float(tin[(size_t)av * DD]);
    const float lam = wv * f;
    float ls = lam;
#pragma unroll
    for (int m = 1; m < 32; m <<= 1) ls += __shfl_xor(ls, m, 64);

    float km0 = 0.f, km1 = 0.f;
#pragma unroll
    for (int j = 0; j < KK; ++j) {
        const float cj = __shfl(lam, j, 64);
        const __half2 hh = *(const __half2*)&vbits[j];
        const float2 v = __half22float2(hh);
        km0 = fmaf(cj, v.x, km0);
        km1 = fmaf(cj, v.y, km1);
    }
    const float rl = 1.f / ls;
    const float m0 = km0 * rl;
    const float m1 = km1 * rl;
    float c2 = (lane ? m0 * m0 : 0.f) + m1 * m1;
    const float kn2 = fminf(waveReduceSum(c2), 0.9f);
    const float invs = 1.f / sqrtf(1.f - kn2);
    const float pd = invs + 1.f;
    const float p0 = lane ? seluf(m0 * invs / pd) : 0.f;
    const float p1 = seluf(m1 * invs / pd);
    float pc = p0 * p0 + p1 * p1;
    const float pn = waveReduceSum(pc);
    const float rdn = 1.f / (1.f - pn + 1e-6f);
    const float tm = sqrtf(1.f + 4.f * pn * rdn * rdn);
    const float ox = lane ? 2.f * p0 * rdn : tm;
    const float oy = 2.f * p1 * rdn;
    const _Float16 hx = (_Float16)ox;
    const _Float16 hy = (_Float16)oy;
    f16x2 hi2, lo2;
    hi2[0] = hx; hi2[1] = hy;
    lo2[0] = (_Float16)(ox - (float)hx);
    lo2[1] = (_Float16)(oy - (float)hy);
    *(f16x2*)&hhi_g[(size_t)node * DD + 2 * lane] = hi2;
    *(f16x2*)&hlo_g[(size_t)node * DD + 2 * lane] = lo2;
}

// -------- kernel 2b: table1 = msg_aux(h) from f16 hi/lo, no staging --------
// 4 waves / 16 rows, 2 n-tiles per wave. A-fragments read directly from
// global hi/lo (16-row tile is L1/L2-hot across the 4 waves). No conversions.
__global__ __launch_bounds__(256) void k_msg(
    const _Float16* __restrict__ hhi_g, const _Float16* __restrict__ hlo_g,
    const _Float16* __restrict__ Lt, __half* __restrict__ tout)
{
    __shared__ float red[4][16];
    __shared__ float m0s[16];
    const int wv_ = threadIdx.x >> 6;
    const int lane = threadIdx.x & 63;
    const int g = lane >> 4, c16 = lane & 15;
    const int baseRow = blockIdx.x * 16;
    const int nb = wv_ * 2;
    const int arow = baseRow + c16;

    f16x8 mh[4], ml[4];
#pragma unroll
    for (int ks = 0; ks < 4; ++ks) {
        mh[ks] = *(const f16x8*)(hhi_g + (size_t)arow * DD + ks * 32 + g * 8);
        ml[ks] = *(const f16x8*)(hlo_g + (size_t)arow * DD + ks * 32 + g * 8);
    }
    f16x8 bl0[4], bl1[4];
#pragma unroll
    for (int ks = 0; ks < 4; ++ks) {
        bl0[ks] = *(const f16x8*)(Lt + (size_t)((nb + 0) * 16 + c16) * DD + ks * 32 + g * 8);
        bl1[ks] = *(const f16x8*)(Lt + (size_t)((nb + 1) * 16 + c16) * DD + ks * 32 + g * 8);
    }
    f32x4v acc[2];
    acc[0] = acc[1] = f32x4v{0.f, 0.f, 0.f, 0.f};
#pragma unroll
    for (int ks = 0; ks < 4; ++ks) {
        acc[0] = __builtin_amdgcn_mfma_f32_16x16x32_f16(mh[ks], bl0[ks], acc[0], 0, 0, 0);
        acc[0] = __builtin_amdgcn_mfma_f32_16x16x32_f16(ml[ks], bl0[ks], acc[0], 0, 0, 0);
        acc[1] = __builtin_amdgcn_mfma_f32_16x16x32_f16(mh[ks], bl1[ks], acc[1], 0, 0, 0);
        acc[1] = __builtin_amdgcn_mfma_f32_16x16x32_f16(ml[ks], bl1[ks], acc[1], 0, 0, 0);
    }

#pragma unroll
    for (int r = 0; r < 4; ++r) {
        float part = 0.f;
#pragma unroll
        for (int n = 0; n < 2; ++n) {
            float sq = acc[n][r] * acc[n][r];
            if (wv_ == 0 && n == 0 && c16 == 0) sq = 0.f;   // time slot
            part += sq;
        }
#pragma unroll
        for (int m = 1; m < 16; m <<= 1) part += __shfl_xor(part, m, 64);
        if (c16 == 0) red[wv_][4 * g + r] = part;
        if (wv_ == 0 && c16 == 0) m0s[4 * g + r] = acc[0][r];
    }
    __syncthreads();
#pragma unroll
    for (int r = 0; r < 4; ++r) {
        const int lrow = 4 * g + r;
        const int row = baseRow + lrow;
        const float rn = 1.f / m0s[lrow];
        const float sum2 = red[0][lrow] + red[1][lrow] + red[2][lrow] + red[3][lrow];
        float kn = sum2 * rn * rn;
        kn = fminf(fmaxf(kn, 0.f), 0.9f);
        const float fh = 1.f / sqrtf(1.f - kn);
#pragma unroll
        for (int n = 0; n < 2; ++n) {
            const float val = (wv_ == 0 && n == 0 && c16 == 0) ? fh : acc[n][r] * rn;
            tout[(size_t)row * DD + (nb + n) * 16 + c16] = __float2half(val);
        }
    }
}

// -------- kernel 3: final gather + mean + activation + normalize -----------
__global__ __launch_bounds__(256) void k_layer(
    const __half* __restrict__ table, const int* __restrict__ adj,
    const float* __restrict__ w, float* __restrict__ out)
{
    const int wave = threadIdx.x >> 6;
    const int lane = threadIdx.x & 63;
    const int node = blockIdx.x * 4 + wave;

    const int   av = adj[node * KK + (lane & 31)];
    const float wv = w[node * KK + (lane & 31)];

    unsigned int vbits[32];
#pragma unroll
    for (int j = 0; j < KK; ++j) {
        const int idx = __shfl(av, j, 64);
        vbits[j] = *(const unsigned int*)(table + (size_t)idx * DD + lane * 2);
    }

    const float f  = __half2float(table[(size_t)av * DD]);
    const float lam = wv * f;
    float ls = lam;
#pragma unroll
    for (int m = 1; m < 32; m <<= 1) ls += __shfl_xor(ls, m, 64);

    float km0 = 0.f, km1 = 0.f;
#pragma unroll
    for (int j = 0; j < KK; ++j) {
        const float cj = __shfl(lam, j, 64);
        const __half2 hh = *(const __half2*)&vbits[j];
        const float2 v = __half22float2(hh);
        km0 = fmaf(cj, v.x, km0);
        km1 = fmaf(cj, v.y, km1);
    }
    const float rl = 1.f / ls;
    const float m0 = km0 * rl;
    const float m1 = km1 * rl;
    float c2 = (lane ? m0 * m0 : 0.f) + m1 * m1;
    const float kn2 = fminf(waveReduceSum(c2), 0.9f);
    const float invs = 1.f / sqrtf(1.f - kn2);
    const float pd = invs + 1.f;
    const float p0 = lane ? seluf(m0 * invs / pd) : 0.f;
    const float p1 = seluf(m1 * invs / pd);
    float pc = p0 * p0 + p1 * p1;
    const float pn = waveReduceSum(pc);
    const float rdn = 1.f / (1.f - pn + 1e-6f);
    const float tm = sqrtf(1.f + 4.f * pn * rdn * rdn);
    float2 o;
    o.x = lane ? 2.f * p0 * rdn : tm;
    o.y = 2.f * p1 * rdn;
    *(float2*)(out + (size_t)node * DD + lane * 2) = o;
}

extern "C" void kernel_launch(void* const* d_in, const int* in_sizes, int n_in,
                              void* d_out, int out_size, void* d_ws, size_t ws_size,
                              hipStream_t stream) {
    const float* x     = (const float*)d_in[0];
    const int*   adj   = (const int*)d_in[1];
    const float* w     = (const float*)d_in[2];
    const float* lin_W = (const float*)d_in[3];
    const float* lin_b = (const float*)d_in[4];
    const float* M     = (const float*)d_in[5];
    float*  out   = (float*)d_out;
    char*   ws    = (char*)d_ws;
    __half*   table0 = (__half*)ws;                  // 7,680,000 B
    __half*   table1 = (__half*)(ws + 7680000);      // 7,680,000 B
    _Float16* Wt     = (_Float16*)(ws + 15360000);   //    65,536 B
    _Float16* Lt     = (_Float16*)(ws + 15425536);   //    32,768 B
    // h transported as exact f16 hi/lo pair inside d_out's 15.36 MB
    _Float16* hhi_g  = (_Float16*)d_out;             // 7,680,000 B
    _Float16* hlo_g  = (_Float16*)((char*)d_out + 7680000);

    k_prep<<<256, 256, 0, stream>>>(lin_W, M, Wt, Lt);
    k_lin_exp_msg<<<NB16, 256, 0, stream>>>(x, Wt, lin_b, Lt, table0);    // layer-0 table
    k_layer_h<<<NN / 4, 256, 0, stream>>>(table0, adj, w, hhi_g, hlo_g);  // layer-0 agg -> h (f16 hi/lo)
    k_msg<<<NB16, 256, 0, stream>>>(hhi_g, hlo_g, Lt, table1);            // layer-1 msg table
    k_layer<<<NN / 4, 256, 0, stream>>>(table1, adj, w, out);             // layer-1 agg -> out
}

// Round 20
// 113.047 us; speedup vs baseline: 1.0560x; 1.0560x over previous
//
#include <hip/hip_runtime.h>
#include <hip/hip_fp16.h>
#include <math.h>

#define NN 30000
#define KK 32
#define FF 256
#define DD 128
#define NB16 1875   // 30000 / 16 exactly
#define SA 268      // padded f16 row stride for LDS fragment arrays

typedef _Float16 f16x8 __attribute__((ext_vector_type(8)));
typedef _Float16 f16x2 __attribute__((ext_vector_type(2)));
typedef float f32x4v __attribute__((ext_vector_type(4)));

__device__ __forceinline__ float seluf(float x) {
    const float scale = 1.0507009873554804934193349852946f;
    const float alpha = 1.6732632423543772848170429916717f;
    return x > 0.f ? scale * x : scale * alpha * expm1f(x);
}

__device__ __forceinline__ float waveReduceSum(float v) {
#pragma unroll
    for (int m = 1; m < 64; m <<= 1) v += __shfl_xor(v, m, 64);
    return v;
}

// -------- kernel 0: transposed f16 weight tables ---------------------------
__global__ __launch_bounds__(256) void k_prep(
    const float* __restrict__ W, const float* __restrict__ M,
    _Float16* __restrict__ Wt, _Float16* __restrict__ Lt)
{
    const int b = blockIdx.x, t = threadIdx.x;
    if (b < 128) {
        Wt[b * FF + t] = (_Float16)W[t * DD + b];
    } else if (t < 128) {
        const int c = b - 128, k = t;
        const float v = (k == 0 && c == 0) ? 1.f
                      : ((k >= 1 && c >= 1) ? M[(k - 1) * 127 + (c - 1)] : 0.f);
        Lt[c * DD + k] = (_Float16)v;
    }
}

// -------- kernel 1: table0 = msg_aux(normalize(expmap(selu(x@W+b))) @ lw) --
// 4 waves / 16 rows; wave owns 32 cols (2 n-tiles). Cooperative LDS A-staging
// (each wave converts its k-slice once), explicit B-fragment hoisting.
__global__ __launch_bounds__(256) void k_lin_exp_msg(
    const float* __restrict__ x, const _Float16* __restrict__ Wt,
    const float* __restrict__ b, const _Float16* __restrict__ Lt,
    __half* __restrict__ table)
{
    __shared__ _Float16 as_[16][SA];
    __shared__ _Float16 hhi[16][SA];
    __shared__ _Float16 hlo[16][SA];
    __shared__ float red[4][16];
    __shared__ float m0s[16];
    const int wv_ = threadIdx.x >> 6;
    const int lane = threadIdx.x & 63;
    const int g = lane >> 4, c16 = lane & 15;
    const int baseRow = blockIdx.x * 16;
    const int nb = wv_ * 2;
    const int arow = baseRow + c16;

    {
        const float4* xp = (const float4*)(x + (size_t)arow * FF);
#pragma unroll
        for (int i = 0; i < 2; ++i) {
            const int ks = wv_ * 2 + i;
            const float4 f0 = xp[ks * 8 + g * 2];
            const float4 f1 = xp[ks * 8 + g * 2 + 1];
            const float q[8] = {f0.x, f0.y, f0.z, f0.w, f1.x, f1.y, f1.z, f1.w};
            f16x8 a;
#pragma unroll
            for (int j = 0; j < 8; ++j) a[j] = (_Float16)q[j];
            *(f16x8*)&as_[c16][ks * 32 + g * 8] = a;
        }
    }
    __syncthreads();

    f16x8 bw0[8], bw1[8];
#pragma unroll
    for (int ks = 0; ks < 8; ++ks) {
        bw0[ks] = *(const f16x8*)(Wt + (size_t)((nb + 0) * 16 + c16) * FF + ks * 32 + g * 8);
        bw1[ks] = *(const f16x8*)(Wt + (size_t)((nb + 1) * 16 + c16) * FF + ks * 32 + g * 8);
    }
    f16x8 af[8];
#pragma unroll
    for (int ks = 0; ks < 8; ++ks)
        af[ks] = *(const f16x8*)&as_[c16][ks * 32 + g * 8];

    f32x4v acc[2];
    acc[0] = acc[1] = f32x4v{0.f, 0.f, 0.f, 0.f};
#pragma unroll
    for (int ks = 0; ks < 8; ++ks) {
        acc[0] = __builtin_amdgcn_mfma_f32_16x16x32_f16(af[ks], bw0[ks], acc[0], 0, 0, 0);
        acc[1] = __builtin_amdgcn_mfma_f32_16x16x32_f16(af[ks], bw1[ks], acc[1], 0, 0, 0);
    }

    float bias[2];
#pragma unroll
    for (int n = 0; n < 2; ++n) bias[n] = b[(nb + n) * 16 + c16];

    float vv[4][2];
#pragma unroll
    for (int r = 0; r < 4; ++r) {
        float part = 0.f;
#pragma unroll
        for (int n = 0; n < 2; ++n) {
            vv[r][n] = seluf(acc[n][r] + bias[n]);
            float sq = vv[r][n] * vv[r][n];
            if (wv_ == 0 && n == 0 && c16 == 0) sq = 0.f;   // exclude d=0
            part += sq;
        }
#pragma unroll
        for (int m = 1; m < 16; m <<= 1) part += __shfl_xor(part, m, 64);
        if (c16 == 0) red[wv_][4 * g + r] = part;
    }
    __syncthreads();
#pragma unroll
    for (int r = 0; r < 4; ++r) {
        const int lrow = 4 * g + r;
        const float ldv = red[0][lrow] + red[1][lrow] + red[2][lrow] + red[3][lrow];
        const float nd = sqrtf(fmaxf(ldv + 1e-9f, 1e-10f));
        const float t  = fminf(nd, 1.0f);
        const float sc = sinhf(t) / nd;
        const float tm = sqrtf(1.f + sc * sc * ldv);
#pragma unroll
        for (int n = 0; n < 2; ++n) {
            const int col = (nb + n) * 16 + c16;
            const float o = (wv_ == 0 && n == 0 && c16 == 0) ? tm : sc * vv[r][n];
            const _Float16 hi = (_Float16)o;
            hhi[lrow][col] = hi;
            hlo[lrow][col] = (_Float16)(o - (float)hi);
        }
    }
    __syncthreads();

    f16x8 bl0[4], bl1[4];
#pragma unroll
    for (int ks = 0; ks < 4; ++ks) {
        bl0[ks] = *(const f16x8*)(Lt + (size_t)((nb + 0) * 16 + c16) * DD + ks * 32 + g * 8);
        bl1[ks] = *(const f16x8*)(Lt + (size_t)((nb + 1) * 16 + c16) * DD + ks * 32 + g * 8);
    }
    f16x8 mh[4], ml[4];
#pragma unroll
    for (int ks = 0; ks < 4; ++ks) {
        mh[ks] = *(const f16x8*)&hhi[c16][ks * 32 + g * 8];
        ml[ks] = *(const f16x8*)&hlo[c16][ks * 32 + g * 8];
    }
    acc[0] = acc[1] = f32x4v{0.f, 0.f, 0.f, 0.f};
#pragma unroll
    for (int ks = 0; ks < 4; ++ks) {
        acc[0] = __builtin_amdgcn_mfma_f32_16x16x32_f16(mh[ks], bl0[ks], acc[0], 0, 0, 0);
        acc[0] = __builtin_amdgcn_mfma_f32_16x16x32_f16(ml[ks], bl0[ks], acc[0], 0, 0, 0);
        acc[1] = __builtin_amdgcn_mfma_f32_16x16x32_f16(mh[ks], bl1[ks], acc[1], 0, 0, 0);
        acc[1] = __builtin_amdgcn_mfma_f32_16x16x32_f16(ml[ks], bl1[ks], acc[1], 0, 0, 0);
    }

#pragma unroll
    for (int r = 0; r < 4; ++r) {
        float part = 0.f;
#pragma unroll
        for (int n = 0; n < 2; ++n) {
            float sq = acc[n][r] * acc[n][r];
            if (wv_ == 0 && n == 0 && c16 == 0) sq = 0.f;   // time slot
            part += sq;
        }
#pragma unroll
        for (int m = 1; m < 16; m <<= 1) part += __shfl_xor(part, m, 64);
        if (c16 == 0) red[wv_][4 * g + r] = part;
        if (wv_ == 0 && c16 == 0) m0s[4 * g + r] = acc[0][r];
    }
    __syncthreads();
#pragma unroll
    for (int r = 0; r < 4; ++r) {
        const int lrow = 4 * g + r;
        const int row = baseRow + lrow;
        const float rn = 1.f / m0s[lrow];
        const float sum2 = red[0][lrow] + red[1][lrow] + red[2][lrow] + red[3][lrow];
        float kn = sum2 * rn * rn;
        kn = fminf(fmaxf(kn, 0.f), 0.9f);
        const float fh = 1.f / sqrtf(1.f - kn);
#pragma unroll
        for (int n = 0; n < 2; ++n) {
            const float val = (wv_ == 0 && n == 0 && c16 == 0) ? fh : acc[n][r] * rn;
            table[(size_t)row * DD + (nb + n) * 16 + c16] = __float2half(val);
        }
    }
}

// -------- kernel 2: fused layer-0 aggregation + layer-1 msg ----------------
// 4 waves x 16 nodes/block. Each wave serially processes 4 nodes (gather +
// hyperbolic mean + activation + normalize), writes h rows as exact hi/lo
// f16 into LDS; then the msg-MFMA phase produces the layer-1 table.
__global__ __launch_bounds__(256) void k_layer_msg(
    const __half* __restrict__ tin, const int* __restrict__ adj,
    const float* __restrict__ w, const _Float16* __restrict__ Lt,
    __half* __restrict__ tout)
{
    __shared__ _Float16 hhi[16][SA];
    __shared__ _Float16 hlo[16][SA];
    __shared__ float red[4][16];
    __shared__ float m0s[16];
    const int wv_ = threadIdx.x >> 6;
    const int lane = threadIdx.x & 63;
    const int g = lane >> 4, c16 = lane & 15;
    const int baseNode = blockIdx.x * 16;

#pragma unroll
    for (int q = 0; q < 4; ++q) {
        const int node = baseNode + wv_ * 4 + q;
        const int   av = adj[node * KK + (lane & 31)];
        const float wvv = w[node * KK + (lane & 31)];

        unsigned int vbits[32];
#pragma unroll
        for (int j = 0; j < KK; ++j) {
            const int idx = __shfl(av, j, 64);
            vbits[j] = *(const unsigned int*)(tin + (size_t)idx * DD + lane * 2);
        }
        const float f = __half2float(tin[(size_t)av * DD]);
        const float lam = wvv * f;
        float ls = lam;
#pragma unroll
        for (int m = 1; m < 32; m <<= 1) ls += __shfl_xor(ls, m, 64);

        float km0 = 0.f, km1 = 0.f;
#pragma unroll
        for (int j = 0; j < KK; ++j) {
            const float cj = __shfl(lam, j, 64);
            const __half2 hh = *(const __half2*)&vbits[j];
            const float2 v = __half22float2(hh);
            km0 = fmaf(cj, v.x, km0);
            km1 = fmaf(cj, v.y, km1);
        }
        const float rl = 1.f / ls;
        const float m0 = km0 * rl;
        const float m1 = km1 * rl;
        float c2 = (lane ? m0 * m0 : 0.f) + m1 * m1;
        const float kn2 = fminf(waveReduceSum(c2), 0.9f);
        const float invs = 1.f / sqrtf(1.f - kn2);
        const float pd = invs + 1.f;
        const float p0 = lane ? seluf(m0 * invs / pd) : 0.f;
        const float p1 = seluf(m1 * invs / pd);
        float pc = p0 * p0 + p1 * p1;
        const float pn = waveReduceSum(pc);
        const float rdn = 1.f / (1.f - pn + 1e-6f);
        const float tm = sqrtf(1.f + 4.f * pn * rdn * rdn);
        const float ox = lane ? 2.f * p0 * rdn : tm;
        const float oy = 2.f * p1 * rdn;
        const int lrow = wv_ * 4 + q;
        const _Float16 hx = (_Float16)ox;
        const _Float16 hy = (_Float16)oy;
        f16x2 hi2, lo2;
        hi2[0] = hx; hi2[1] = hy;
        lo2[0] = (_Float16)(ox - (float)hx);
        lo2[1] = (_Float16)(oy - (float)hy);
        *(f16x2*)&hhi[lrow][2 * lane] = hi2;
        *(f16x2*)&hlo[lrow][2 * lane] = lo2;
    }
    __syncthreads();

    // ---- msg phase ----
    const int nb = wv_ * 2;
    f16x8 bl0[4], bl1[4];
#pragma unroll
    for (int ks = 0; ks < 4; ++ks) {
        bl0[ks] = *(const f16x8*)(Lt + (size_t)((nb + 0) * 16 + c16) * DD + ks * 32 + g * 8);
        bl1[ks] = *(const f16x8*)(Lt + (size_t)((nb + 1) * 16 + c16) * DD + ks * 32 + g * 8);
    }
    f16x8 mh[4], ml[4];
#pragma unroll
    for (int ks = 0; ks < 4; ++ks) {
        mh[ks] = *(const f16x8*)&hhi[c16][ks * 32 + g * 8];
        ml[ks] = *(const f16x8*)&hlo[c16][ks * 32 + g * 8];
    }
    f32x4v acc[2];
    acc[0] = acc[1] = f32x4v{0.f, 0.f, 0.f, 0.f};
#pragma unroll
    for (int ks = 0; ks < 4; ++ks) {
        acc[0] = __builtin_amdgcn_mfma_f32_16x16x32_f16(mh[ks], bl0[ks], acc[0], 0, 0, 0);
        acc[0] = __builtin_amdgcn_mfma_f32_16x16x32_f16(ml[ks], bl0[ks], acc[0], 0, 0, 0);
        acc[1] = __builtin_amdgcn_mfma_f32_16x16x32_f16(mh[ks], bl1[ks], acc[1], 0, 0, 0);
        acc[1] = __builtin_amdgcn_mfma_f32_16x16x32_f16(ml[ks], bl1[ks], acc[1], 0, 0, 0);
    }

#pragma unroll
    for (int r = 0; r < 4; ++r) {
        float part = 0.f;
#pragma unroll
        for (int n = 0; n < 2; ++n) {
            float sq = acc[n][r] * acc[n][r];
            if (wv_ == 0 && n == 0 && c16 == 0) sq = 0.f;   // time slot
            part += sq;
        }
#pragma unroll
        for (int m = 1; m < 16; m <<= 1) part += __shfl_xor(part, m, 64);
        if (c16 == 0) red[wv_][4 * g + r] = part;
        if (wv_ == 0 && c16 == 0) m0s[4 * g + r] = acc[0][r];
    }
    __syncthreads();
#pragma unroll
    for (int r = 0; r < 4; ++r) {
        const int lrow = 4 * g + r;
        const int row = baseNode + lrow;
        const float rn = 1.f / m0s[lrow];
        const float sum2 = red[0][lrow] + red[1][lrow] + red[2][lrow] + red[3][lrow];
        float kn = sum2 * rn * rn;
        kn = fminf(fmaxf(kn, 0.f), 0.9f);
        const float fh = 1.f / sqrtf(1.f - kn);
#pragma unroll
        for (int n = 0; n < 2; ++n) {
            const float val = (wv_ == 0 && n == 0 && c16 == 0) ? fh : acc[n][r] * rn;
            tout[(size_t)row * DD + (nb + n) * 16 + c16] = __float2half(val);
        }
    }
}

// -------- kernel 3: final gather + mean + activation + normalize -----------
__global__ __launch_bounds__(256) void k_layer(
    const __half* __restrict__ table, const int* __restrict__ adj,
    const float* __restrict__ w, float* __restrict__ out)
{
    const int wave = threadIdx.x >> 6;
    const int lane = threadIdx.x & 63;
    const int node = blockIdx.x * 4 + wave;

    const int   av = adj[node * KK + (lane & 31)];
    const float wv = w[node * KK + (lane & 31)];

    unsigned int vbits[32];
#pragma unroll
    for (int j = 0; j < KK; ++j) {
        const int idx = __shfl(av, j, 64);
        vbits[j] = *(const unsigned int*)(table + (size_t)idx * DD + lane * 2);
    }

    const float f  = __half2float(table[(size_t)av * DD]);
    const float lam = wv * f;
    float ls = lam;
#pragma unroll
    for (int m = 1; m < 32; m <<= 1) ls += __shfl_xor(ls, m, 64);

    float km0 = 0.f, km1 = 0.f;
#pragma unroll
    for (int j = 0; j < KK; ++j) {
        const float cj = __shfl(lam, j, 64);
        const __half2 hh = *(const __half2*)&vbits[j];
        const float2 v = __half22float2(hh);
        km0 = fmaf(cj, v.x, km0);
        km1 = fmaf(cj, v.y, km1);
    }
    const float rl = 1.f / ls;
    const float m0 = km0 * rl;
    const float m1 = km1 * rl;
    float c2 = (lane ? m0 * m0 : 0.f) + m1 * m1;
    const float kn2 = fminf(waveReduceSum(c2), 0.9f);
    const float invs = 1.f / sqrtf(1.f - kn2);
    const float pd = invs + 1.f;
    const float p0 = lane ? seluf(m0 * invs / pd) : 0.f;
    const float p1 = seluf(m1 * invs / pd);
    float pc = p0 * p0 + p1 * p1;
    const float pn = waveReduceSum(pc);
    const float rdn = 1.f / (1.f - pn + 1e-6f);
    const float tm = sqrtf(1.f + 4.f * pn * rdn * rdn);
    float2 o;
    o.x = lane ? 2.f * p0 * rdn : tm;
    o.y = 2.f * p1 * rdn;
    *(float2*)(out + (size_t)node * DD + lane * 2) = o;
}

extern "C" void kernel_launch(void* const* d_in, const int* in_sizes, int n_in,
                              void* d_out, int out_size, void* d_ws, size_t ws_size,
                              hipStream_t stream) {
    const float* x     = (const float*)d_in[0];
    const int*   adj   = (const int*)d_in[1];
    const float* w     = (const float*)d_in[2];
    const float* lin_W = (const float*)d_in[3];
    const float* lin_b = (const float*)d_in[4];
    const float* M     = (const float*)d_in[5];
    float*  out   = (float*)d_out;
    char*   ws    = (char*)d_ws;
    __half*   table0 = (__half*)ws;                  // 7,680,000 B
    __half*   table1 = (__half*)(ws + 7680000);      // 7,680,000 B
    _Float16* Wt     = (_Float16*)(ws + 15360000);   //    65,536 B
    _Float16* Lt     = (_Float16*)(ws + 15425536);   //    32,768 B

    k_prep<<<256, 256, 0, stream>>>(lin_W, M, Wt, Lt);
    k_lin_exp_msg<<<NB16, 256, 0, stream>>>(x, Wt, lin_b, Lt, table0);   // layer-0 table
    k_layer_msg<<<NB16, 256, 0, stream>>>(table0, adj, w, Lt, table1);   // layer-0 agg + layer-1 msg
    k_layer<<<NN / 4, 256, 0, stream>>>(table1, adj, w, out);            // layer-1 agg -> out
}